// Round 9
// baseline (783.371 us; speedup 1.0000x reference)
//
#include <hip/hip_runtime.h>

#define HDIM 192
#define EPS 1e-5f

typedef __attribute__((ext_vector_type(8))) _Float16 half8;
typedef __attribute__((ext_vector_type(4))) float floatx4;

__device__ __forceinline__ float h2f(ushort u) {
    union { ushort u; _Float16 h; } c; c.u = u; return (float)c.h;
}
__device__ __forceinline__ ushort f2h(float x) {
    _Float16 h = (_Float16)x;           // RTN
    union { _Float16 h; ushort u; } c; c.h = h; return c.u;
}
// split fp32 into fp16 hi + fp16 lo (RTN; combined rel err ~2^-22)
__device__ __forceinline__ void splitf(float x, ushort& hi, ushort& lo) {
    hi = f2h(x);
    lo = f2h(x - h2f(hi));
}
__device__ __forceinline__ uint4 pack8(const ushort* h) {
    uint4 p;
    p.x = h[0] | ((uint)h[1] << 16); p.y = h[2] | ((uint)h[3] << 16);
    p.z = h[4] | ((uint)h[5] << 16); p.w = h[6] | ((uint)h[7] << 16);
    return p;
}

// Activation planes are CHUNK-PLANAR: element (row, c) lives at
// ((c/32)*Nrow + row)*32 + c%32.  A-fragment loads in the GEMM then read a
// contiguous 1KB block per wave (perfect coalescing) instead of 16 scattered
// 64B lines (the round-4..8 ~110us plateau).

// ---------------------------------------------------------------------------
// Weight prep: W[K,192] fp32 (nmat stacked) -> frag-ordered fp16 hi/lo planes.
// Per k-chunk (32 k): [plane(hi,lo)][ct(12)][lane(64)][j(8)] = 12288 ushorts.
// B-frag layout of mfma_f32_16x16x32_f16: n=lane&15, k=(lane>>4)*8+j.
// ---------------------------------------------------------------------------
__global__ __launch_bounds__(256) void prep_w_k(
    const float* __restrict__ W, ushort* __restrict__ Wf, int K, int nmat)
{
    int perMat = (K >> 5) * 12 * 64;
    int idx = blockIdx.x * 256 + threadIdx.x;
    if (idx >= perMat * nmat) return;
    int mat = idx / perMat;
    int r = idx - mat * perMat;
    int lane = r & 63;
    int ct = (r >> 6) % 12;
    int kc = r / (12 * 64);
    int col = ct * 16 + (lane & 15);
    int kb  = kc * 32 + (lane >> 4) * 8;
    const float* Wm = W + (size_t)mat * K * HDIM;
    ushort* base = Wf + (size_t)mat * K * HDIM * 2;
    size_t o = (size_t)kc * 12288 + (size_t)(ct * 64 + lane) * 8;
    #pragma unroll
    for (int j = 0; j < 8; ++j) {
        ushort hi, lo;
        splitf(Wm[(size_t)(kb + j) * HDIM + col], hi, lo);
        base[o + j]        = hi;
        base[o + 6144 + j] = lo;
    }
}

// ---------------------------------------------------------------------------
// fp32 row-major [R, C] -> fp16 chunk-planar (C multiple of 32; C==32 is
// identical to row-major). One thread per 8 channels.
// ---------------------------------------------------------------------------
__global__ __launch_bounds__(256) void conv_planar_k(
    const float* __restrict__ src, ushort* __restrict__ dst, int R, int C)
{
    int OC = C >> 3;                        // octets per row
    int idx = blockIdx.x * 256 + threadIdx.x;
    if (idx >= R * OC) return;
    int r = idx / OC;
    int o = idx - r * OC;
    float4 v0 = ((const float4*)(src + (size_t)r * C + o * 8))[0];
    float4 v1 = ((const float4*)(src + (size_t)r * C + o * 8))[1];
    float v[8] = {v0.x, v0.y, v0.z, v0.w, v1.x, v1.y, v1.z, v1.w};
    ushort h[8];
    #pragma unroll
    for (int t = 0; t < 8; ++t) h[t] = f2h(v[t]);
    *(uint4*)(dst + ((size_t)(o >> 2) * R + r) * 32 + (o & 3) * 8) = pack8(h);
}

// ---------------------------------------------------------------------------
// MFMA GEMM: C[N,192] = A1@W1 (+ A2@W2) + bias-term, optional fused BN stats.
// Block: 256 thr / 4 waves, tile 64 rows x 192 cols; wave tile 64x48.
// A planes chunk-planar fp16 (coalesced 1KB frag loads); B frag-major from
// global (L2-hot). No LDS staging, no K-loop barriers.
// fp16 2-term: Ah*Bh + Ah*Bl (W split hi/lo).
// ---------------------------------------------------------------------------
template<bool DUAL, bool RELU, bool DEG, bool STATS>
__global__ __launch_bounds__(256, 4) void gemm_mfma_k(
    const ushort* __restrict__ A1h, const ushort* __restrict__ W1f,
    const ushort* __restrict__ A2h, const ushort* __restrict__ W2f,
    const float* __restrict__ degf, const float* __restrict__ bias,
    float* __restrict__ C, float* __restrict__ stats, int N, int K)
{
    __shared__ float sstat[2][HDIM];
    const int tid  = threadIdx.x;
    const int wave = tid >> 6;      // 0..3 = column group (48 cols each)
    const int lane = tid & 63;
    const int row0 = blockIdx.x * 64;
    const int m16 = lane & 15;
    const int g4  = lane >> 4;

    if (STATS && tid < HDIM) { sstat[0][tid] = 0.f; sstat[1][tid] = 0.f; }

    int rowid[4];
    #pragma unroll
    for (int s = 0; s < 4; ++s) {
        int rr = row0 + s * 16 + m16; if (rr >= N) rr = N - 1;
        rowid[s] = rr;
    }

    floatx4 acc[4][3];
    #pragma unroll
    for (int s = 0; s < 4; ++s)
        #pragma unroll
        for (int ct = 0; ct < 3; ++ct) acc[s][ct] = (floatx4){0.f, 0.f, 0.f, 0.f};

    const int nkc = K >> 5;
    const int nphase = DUAL ? 2 : 1;
    for (int phase = 0; phase < nphase; ++phase) {
        const ushort* Ah = phase ? A2h : A1h;
        const ushort* Wf = phase ? W2f : W1f;
        for (int kc = 0; kc < nkc; ++kc) {
            // B fragments straight from global (frag-major, coalesced, L2-hot)
            const ushort* Wb = Wf + (size_t)kc * 12288 + (size_t)(wave * 3 * 64 + lane) * 8;
            half8 bh[3], bl[3];
            #pragma unroll
            for (int ct = 0; ct < 3; ++ct) {
                bh[ct] = *(const half8*)(Wb + ct * 512);
                bl[ct] = *(const half8*)(Wb + 6144 + ct * 512);
            }
            // A fragments: chunk-planar -> one contiguous 1KB block per wave
            const ushort* Ap = Ah + (size_t)kc * N * 32 + g4 * 8;
            half8 ah[4];
            #pragma unroll
            for (int s = 0; s < 4; ++s)
                ah[s] = *(const half8*)(Ap + (size_t)rowid[s] * 32);
            #pragma unroll
            for (int ct = 0; ct < 3; ++ct) {
                #pragma unroll
                for (int s = 0; s < 4; ++s) {
                    acc[s][ct] = __builtin_amdgcn_mfma_f32_16x16x32_f16(ah[s], bh[ct], acc[s][ct], 0, 0, 0);
                    acc[s][ct] = __builtin_amdgcn_mfma_f32_16x16x32_f16(ah[s], bl[ct], acc[s][ct], 0, 0, 0);
                }
            }
        }
    }

    if (STATS) __syncthreads();   // sstat zero-init visible

    // epilogue: C/D layout col=lane&15, row=(lane>>4)*4+reg  [m89]
    #pragma unroll
    for (int ct = 0; ct < 3; ++ct) {
        int col = wave * 48 + ct * 16 + m16;
        float bv = bias ? bias[col] : 0.f;
        float lsum = 0.f, lsq = 0.f;
        #pragma unroll
        for (int s = 0; s < 4; ++s) {
            #pragma unroll
            for (int reg = 0; reg < 4; ++reg) {
                int rr = row0 + s * 16 + g4 * 4 + reg;
                if (rr < N) {
                    float v = acc[s][ct][reg] + (DEG ? degf[rr] * bv : bv);
                    if (STATS) { lsum += v; lsq += v * v; }
                    if (RELU) v = fmaxf(v, 0.f);
                    C[(size_t)rr * HDIM + col] = v;
                }
            }
        }
        if (STATS) {
            lsum += __shfl_xor(lsum, 16); lsum += __shfl_xor(lsum, 32);
            lsq  += __shfl_xor(lsq, 16);  lsq  += __shfl_xor(lsq, 32);
            if (g4 == 0) {
                atomicAdd(&sstat[0][col], lsum);
                atomicAdd(&sstat[1][col], lsq);
            }
        }
    }
    if (STATS) {
        __syncthreads();
        if (tid < HDIM) {
            atomicAdd(&stats[tid], sstat[0][tid]);
            atomicAdd(&stats[HDIM + tid], sstat[1][tid]);
        }
    }
}

// ---------------------------------------------------------------------------
// CSR construction from edge_dst
// ---------------------------------------------------------------------------
__global__ __launch_bounds__(256) void hist_k(
    const int* __restrict__ dst, int* __restrict__ deg, int E)
{
    int e = blockIdx.x * 256 + threadIdx.x;
    if (e < E) atomicAdd(&deg[dst[e]], 1);
}

__global__ __launch_bounds__(256) void block_sum_k(
    const int* __restrict__ deg, int* __restrict__ bsum, int N)
{
    __shared__ int s[256];
    int t = threadIdx.x;
    int n = blockIdx.x * 256 + t;
    s[t] = (n < N) ? deg[n] : 0;
    __syncthreads();
    for (int off = 128; off > 0; off >>= 1) {
        if (t < off) s[t] += s[t + off];
        __syncthreads();
    }
    if (t == 0) bsum[blockIdx.x] = s[0];
}

__global__ __launch_bounds__(512) void scan_bsum_k(int* __restrict__ bsum, int nb)
{
    __shared__ int s[512];
    int t = threadIdx.x;
    int v = (t < nb) ? bsum[t] : 0;
    s[t] = v;
    __syncthreads();
    for (int off = 1; off < 512; off <<= 1) {
        int u = (t >= off) ? s[t - off] : 0;
        __syncthreads();
        s[t] += u;
        __syncthreads();
    }
    if (t < nb) bsum[t] = s[t] - v;   // exclusive
}

__global__ __launch_bounds__(256) void row_ptr_k(
    const int* __restrict__ deg, const int* __restrict__ bsum,
    int* __restrict__ row_ptr, int* __restrict__ cursor,
    float* __restrict__ degf, int N, int E)
{
    __shared__ int s[256];
    int t = threadIdx.x;
    int n = blockIdx.x * 256 + t;
    int v = (n < N) ? deg[n] : 0;
    s[t] = v;
    __syncthreads();
    for (int off = 1; off < 256; off <<= 1) {
        int u = (t >= off) ? s[t - off] : 0;
        __syncthreads();
        s[t] += u;
        __syncthreads();
    }
    int ex = s[t] - v + bsum[blockIdx.x];
    if (n < N) {
        row_ptr[n] = ex;
        cursor[n]  = ex;
        degf[n]    = (float)v;
    }
    if (blockIdx.x == 0 && t == 0) row_ptr[N] = E;
}

__global__ __launch_bounds__(256) void fill_k(
    const int* __restrict__ src, const int* __restrict__ dst,
    int* __restrict__ cursor, int* __restrict__ col, int E)
{
    int e = blockIdx.x * 256 + threadIdx.x;
    if (e < E) {
        int p = atomicAdd(&cursor[dst[e]], 1);
        col[p] = src[e];
    }
}

// ---------------------------------------------------------------------------
// gather on chunk-planar fp16: g[n] = sum_{j} x[col[j]]; fp32 acc, RTN out.
// One thread per (node, 8-channel octet).
// ---------------------------------------------------------------------------
__global__ __launch_bounds__(256) void gather_h_k(
    const ushort* __restrict__ xh, const int* __restrict__ row_ptr,
    const int* __restrict__ col, ushort* __restrict__ gh, int N, int K)
{
    int OC = K >> 3;
    int idx = blockIdx.x * 256 + threadIdx.x;
    if (idx >= N * OC) return;
    int n = idx / OC;
    int o = idx - n * OC;
    size_t plane = (size_t)(o >> 2) * N * 32 + (o & 3) * 8;   // chunk base + e0
    int j0 = row_ptr[n], j1 = row_ptr[n + 1];
    float acc[8] = {0.f,0.f,0.f,0.f,0.f,0.f,0.f,0.f};
    for (int j = j0; j < j1; ++j) {
        int s = col[j];
        uint4 hv = *(const uint4*)(xh + plane + (size_t)s * 32);
        uint hu[4] = {hv.x, hv.y, hv.z, hv.w};
        #pragma unroll
        for (int t = 0; t < 4; ++t) {
            acc[2*t]   += h2f((ushort)(hu[t] & 0xffffu));
            acc[2*t+1] += h2f((ushort)(hu[t] >> 16));
        }
    }
    ushort oh[8];
    #pragma unroll
    for (int t = 0; t < 8; ++t) oh[t] = f2h(acc[t]);
    *(uint4*)(gh + plane + (size_t)n * 32) = pack8(oh);
}

// ---------------------------------------------------------------------------
// batchnorm finalize + apply (chunk-planar fp16 out)
// ---------------------------------------------------------------------------
__global__ void bn_finalize_k(const float* __restrict__ sums,
                              const float* __restrict__ gamma,
                              const float* __restrict__ beta,
                              float* __restrict__ ss, float invN)
{
    int c = threadIdx.x;
    float mu  = sums[c] * invN;
    float var = sums[HDIM + c] * invN - mu * mu;
    float sc  = gamma[c] * rsqrtf(var + EPS);
    ss[c]        = sc;
    ss[HDIM + c] = beta[c] - mu * sc;
}

__global__ __launch_bounds__(256) void bn_apply_h_k(
    const float* __restrict__ h, const float* __restrict__ ss,
    ushort* __restrict__ xh, int N)
{
    int idx = blockIdx.x * 256 + threadIdx.x;   // over N*24 octets
    if (idx >= N * 24) return;
    int n = idx / 24;
    int o = idx - n * 24;
    int q = o * 8;
    float4 v0 = ((const float4*)h)[idx * 2];
    float4 v1 = ((const float4*)h)[idx * 2 + 1];
    float v[8] = {v0.x, v0.y, v0.z, v0.w, v1.x, v1.y, v1.z, v1.w};
    ushort oh[8];
    #pragma unroll
    for (int t = 0; t < 8; ++t) {
        float r = fmaxf(v[t] * ss[q + t] + ss[HDIM + q + t], 0.f);
        oh[t] = f2h(r);
    }
    *(uint4*)(xh + ((size_t)(o >> 2) * N + n) * 32 + (o & 3) * 8) = pack8(oh);
}

// ---------------------------------------------------------------------------
// pool over contiguous per-graph row ranges (batch sorted), planar input
// ---------------------------------------------------------------------------
__global__ __launch_bounds__(256) void init_start_k(int* __restrict__ start, int G, int N)
{
    int g = blockIdx.x * 256 + threadIdx.x;
    if (g <= G) start[g] = N;
}

__global__ __launch_bounds__(256) void bound_k(
    const int* __restrict__ batch, int* __restrict__ start, int N)
{
    int n = blockIdx.x * 256 + threadIdx.x;
    if (n >= N) return;
    int b  = batch[n];
    int bp = (n == 0) ? -1 : batch[n - 1];
    for (int g = bp + 1; g <= b; ++g) start[g] = n;
}

__global__ __launch_bounds__(192) void pool_k(
    const ushort* __restrict__ xh, const int* __restrict__ start,
    float* __restrict__ gout, int G, int N)
{
    int g = blockIdx.x;
    int c = threadIdx.x;
    const ushort* base = xh + (size_t)(c >> 5) * N * 32 + (c & 31);
    int r0 = start[g], r1 = start[g + 1];
    float s = 0.f;
    for (int r = r0; r < r1; ++r) s += h2f(base[(size_t)r * 32]);
    float cnt = (float)(r1 - r0);
    gout[(size_t)g * HDIM + c] = s / fmaxf(cnt, 1.f);
}

// ---------------------------------------------------------------------------
__global__ __launch_bounds__(64) void out_dot_k(
    const float* __restrict__ g2, const float* __restrict__ Wout,
    const float* __restrict__ bout, float* __restrict__ out, int G)
{
    int gi = blockIdx.x;
    int t = threadIdx.x;
    const float* r = g2 + (size_t)gi * HDIM;
    float s = r[t] * Wout[t] + r[t + 64] * Wout[t + 64] + r[t + 128] * Wout[t + 128];
    #pragma unroll
    for (int off = 32; off > 0; off >>= 1) s += __shfl_down(s, off, 64);
    if (t == 0) out[gi] = s + bout[0];
}

// ---------------------------------------------------------------------------
extern "C" void kernel_launch(void* const* d_in, const int* in_sizes, int n_in,
                              void* d_out, int out_size, void* d_ws, size_t ws_size,
                              hipStream_t stream)
{
    const float* x      = (const float*)d_in[0];
    const int*   esrc   = (const int*)d_in[1];
    const int*   edst   = (const int*)d_in[2];
    const int*   batch  = (const int*)d_in[3];
    const float* Wrel0  = (const float*)d_in[4];
    const float* brel0  = (const float*)d_in[5];
    const float* Wroot0 = (const float*)d_in[6];
    const float* Wrel   = (const float*)d_in[7];
    const float* brel   = (const float*)d_in[8];
    const float* Wroot  = (const float*)d_in[9];
    const float* gamma  = (const float*)d_in[10];
    const float* beta   = (const float*)d_in[11];
    const float* Wh1    = (const float*)d_in[12];
    const float* bh1    = (const float*)d_in[13];
    const float* Wh2    = (const float*)d_in[14];
    const float* bh2    = (const float*)d_in[15];
    const float* Wout   = (const float*)d_in[16];
    const float* bout   = (const float*)d_in[17];
    float* out = (float*)d_out;

    const int N  = in_sizes[3];           // 100000
    const int E  = in_sizes[1];           // 400000
    const int K0 = in_sizes[0] / N;       // 32
    const int G  = out_size;              // 2000
    const int nBlocks = (N + 255) / 256;

    char* p = (char*)d_ws;
    auto carve = [&](size_t bytes) -> void* {
        void* r = (void*)p; p += (bytes + 255) & ~(size_t)255; return r;
    };
    float*  bufa  = (float*) carve((size_t)N * HDIM * 4);
    ushort* xh    = (ushort*)carve((size_t)N * HDIM * 2);
    ushort* gh    = (ushort*)carve((size_t)N * HDIM * 2);
    float*  gsum  = (float*) carve((size_t)G * HDIM * 4);
    float*  g1    = (float*) carve((size_t)G * HDIM * 4);
    float*  g2    = (float*) carve((size_t)G * HDIM * 4);
    ushort* gsh   = (ushort*)carve((size_t)G * HDIM * 2);
    ushort* g1h   = (ushort*)carve((size_t)G * HDIM * 2);
    float*  bnsums= (float*) carve(4 * 2 * HDIM * 4);   // per-layer slices
    float*  bnss  = (float*) carve(2 * HDIM * 4);
    float*  degf  = (float*) carve((size_t)N * 4);
    int*    deg   = (int*)   carve((size_t)N * 4);
    int*    row_ptr=(int*)   carve((size_t)(N + 1) * 4);
    int*    cursor= (int*)   carve((size_t)N * 4);
    int*    col   = (int*)   carve((size_t)E * 4);
    int*    bsum  = (int*)   carve((size_t)nBlocks * 4);
    int*    start = (int*)   carve((size_t)(G + 1) * 4);
    ushort* Wrel0f= (ushort*)carve((size_t)K0 * HDIM * 2 * 2);
    ushort* Wroot0f=(ushort*)carve((size_t)K0 * HDIM * 2 * 2);
    ushort* Wrelf = (ushort*)carve((size_t)3 * HDIM * HDIM * 2 * 2);
    ushort* Wrootf= (ushort*)carve((size_t)3 * HDIM * HDIM * 2 * 2);
    ushort* Wh1f  = (ushort*)carve((size_t)HDIM * HDIM * 2 * 2);
    ushort* Wh2f  = (ushort*)carve((size_t)HDIM * HDIM * 2 * 2);

    dim3 b256(256);
    const int eBlocks = (E + 255) / 256;
    const int gemmN = (N + 63) / 64;
    const int gemmG = (G + 63) / 64;

    // ---- weight prep (frag-ordered fp16 hi/lo split)
    {
        int t0 = (K0 >> 5) * 12 * 64;
        int t1 = (HDIM >> 5) * 12 * 64;
        prep_w_k<<<(t0 + 255) / 256, b256, 0, stream>>>(Wrel0,  Wrel0f,  K0, 1);
        prep_w_k<<<(t0 + 255) / 256, b256, 0, stream>>>(Wroot0, Wroot0f, K0, 1);
        prep_w_k<<<(3 * t1 + 255) / 256, b256, 0, stream>>>(Wrel,  Wrelf,  HDIM, 3);
        prep_w_k<<<(3 * t1 + 255) / 256, b256, 0, stream>>>(Wroot, Wrootf, HDIM, 3);
        prep_w_k<<<(t1 + 255) / 256, b256, 0, stream>>>(Wh1, Wh1f, HDIM, 1);
        prep_w_k<<<(t1 + 255) / 256, b256, 0, stream>>>(Wh2, Wh2f, HDIM, 1);
    }
    // x -> planar fp16 (K0=32: planar == row-major)
    conv_planar_k<<<((N * (K0 >> 3)) + 255) / 256, b256, 0, stream>>>(x, xh, N, K0);

    // ---- CSR build
    hipMemsetAsync(deg, 0, N * sizeof(int), stream);
    hipMemsetAsync(bnsums, 0, 4 * 2 * HDIM * sizeof(float), stream);
    hist_k<<<eBlocks, b256, 0, stream>>>(edst, deg, E);
    block_sum_k<<<nBlocks, b256, 0, stream>>>(deg, bsum, N);
    scan_bsum_k<<<1, dim3(512), 0, stream>>>(bsum, nBlocks);
    row_ptr_k<<<nBlocks, b256, 0, stream>>>(deg, bsum, row_ptr, cursor, degf, N, E);
    fill_k<<<eBlocks, b256, 0, stream>>>(esrc, edst, cursor, col, E);

    // ---- graph boundaries for pooling
    init_start_k<<<(G + 256) / 256, b256, 0, stream>>>(start, G, N);
    bound_k<<<nBlocks, b256, 0, stream>>>(batch, start, N);

    // ---- layers
    for (int l = 0; l < 4; ++l) {
        const int K = (l == 0) ? K0 : HDIM;
        const ushort* Wrf = (l == 0) ? Wrel0f  : Wrelf  + (size_t)(l - 1) * HDIM * HDIM * 2;
        const ushort* Wtf = (l == 0) ? Wroot0f : Wrootf + (size_t)(l - 1) * HDIM * HDIM * 2;
        const float*  br  = (l == 0) ? brel0   : brel   + (size_t)(l - 1) * HDIM;
        float* stats = bnsums + l * 2 * HDIM;

        int gthreads = N * (K >> 3);
        gather_h_k<<<(gthreads + 255) / 256, b256, 0, stream>>>(
            xh, row_ptr, col, gh, N, K);
        gemm_mfma_k<true, false, true, true><<<gemmN, b256, 0, stream>>>(
            gh, Wrf, xh, Wtf, degf, br, bufa, stats, N, K);
        bn_finalize_k<<<1, dim3(192), 0, stream>>>(stats, gamma + l * HDIM,
                                                   beta + l * HDIM, bnss, 1.0f / N);
        bn_apply_h_k<<<(N * 24 + 255) / 256, b256, 0, stream>>>(bufa, bnss, xh, N);
    }

    // ---- pool
    pool_k<<<G, dim3(192), 0, stream>>>(xh, start, gsum, G, N);

    // ---- head MLP (MFMA path, planar activations with Nrow=G)
    conv_planar_k<<<((G * 24) + 255) / 256, b256, 0, stream>>>(gsum, gsh, G, HDIM);
    gemm_mfma_k<false, true, false, false><<<gemmG, b256, 0, stream>>>(
        gsh, Wh1f, nullptr, nullptr, nullptr, bh1, g1, nullptr, G, HDIM);
    conv_planar_k<<<((G * 24) + 255) / 256, b256, 0, stream>>>(g1, g1h, G, HDIM);
    gemm_mfma_k<false, false, false, false><<<gemmG, b256, 0, stream>>>(
        g1h, Wh2f, nullptr, nullptr, nullptr, bh2, g2, nullptr, G, HDIM);
    out_dot_k<<<G, dim3(64), 0, stream>>>(g2, Wout, bout, out, G);
}

// Round 10
// 741.255 us; speedup vs baseline: 1.0568x; 1.0568x over previous
//
#include <hip/hip_runtime.h>

#define HDIM 192
#define EPS 1e-5f

typedef __attribute__((ext_vector_type(8))) _Float16 half8;
typedef __attribute__((ext_vector_type(4))) float floatx4;

__device__ __forceinline__ float h2f(ushort u) {
    union { ushort u; _Float16 h; } c; c.u = u; return (float)c.h;
}
__device__ __forceinline__ ushort f2h(float x) {
    _Float16 h = (_Float16)x;           // RTN
    union { _Float16 h; ushort u; } c; c.h = h; return c.u;
}
__device__ __forceinline__ uint4 pack8(const ushort* h) {
    uint4 p;
    p.x = h[0] | ((uint)h[1] << 16); p.y = h[2] | ((uint)h[3] << 16);
    p.z = h[4] | ((uint)h[5] << 16); p.w = h[6] | ((uint)h[7] << 16);
    return p;
}

// Activation planes are CHUNK-PLANAR: element (row, c) lives at
// ((c/32)*Nrow + row)*32 + c%32.  A-fragment loads in the GEMM read a
// contiguous 1KB block per wave (perfect coalescing).

// ---------------------------------------------------------------------------
// Weight prep: W[K,192] fp32 (nmat stacked) -> frag-ordered SINGLE fp16 plane.
// Per k-chunk (32 k): [ct(12)][lane(64)][j(8)] = 6144 ushorts.
// B-frag layout of mfma_f32_16x16x32_f16: n=lane&15, k=(lane>>4)*8+j.
// ---------------------------------------------------------------------------
__global__ __launch_bounds__(256) void prep_w_k(
    const float* __restrict__ W, ushort* __restrict__ Wf, int K, int nmat)
{
    int perMat = (K >> 5) * 12 * 64;
    int idx = blockIdx.x * 256 + threadIdx.x;
    if (idx >= perMat * nmat) return;
    int mat = idx / perMat;
    int r = idx - mat * perMat;
    int lane = r & 63;
    int ct = (r >> 6) % 12;
    int kc = r / (12 * 64);
    int col = ct * 16 + (lane & 15);
    int kb  = kc * 32 + (lane >> 4) * 8;
    const float* Wm = W + (size_t)mat * K * HDIM;
    ushort* base = Wf + (size_t)mat * K * HDIM;
    size_t o = (size_t)kc * 6144 + (size_t)(ct * 64 + lane) * 8;
    #pragma unroll
    for (int j = 0; j < 8; ++j)
        base[o + j] = f2h(Wm[(size_t)(kb + j) * HDIM + col]);
}

// ---------------------------------------------------------------------------
// fp32 row-major [R, C] -> fp16 chunk-planar (C multiple of 32; C==32 is
// identical to row-major). One thread per 8 channels.
// ---------------------------------------------------------------------------
__global__ __launch_bounds__(256) void conv_planar_k(
    const float* __restrict__ src, ushort* __restrict__ dst, int R, int C)
{
    int OC = C >> 3;                        // octets per row
    int idx = blockIdx.x * 256 + threadIdx.x;
    if (idx >= R * OC) return;
    int r = idx / OC;
    int o = idx - r * OC;
    float4 v0 = ((const float4*)(src + (size_t)r * C + o * 8))[0];
    float4 v1 = ((const float4*)(src + (size_t)r * C + o * 8))[1];
    float v[8] = {v0.x, v0.y, v0.z, v0.w, v1.x, v1.y, v1.z, v1.w};
    ushort h[8];
    #pragma unroll
    for (int t = 0; t < 8; ++t) h[t] = f2h(v[t]);
    *(uint4*)(dst + ((size_t)(o >> 2) * R + r) * 32 + (o & 3) * 8) = pack8(h);
}

// ---------------------------------------------------------------------------
// MFMA GEMM: C[N,192] = A1@W1 (+ A2@W2) + bias-term, optional fused BN stats.
// Block: 256 thr / 4 waves, tile 64 rows x 192 cols; wave tile 64x48.
// A chunk-planar fp16 (coalesced 1KB frag loads); W single fp16 plane,
// frag-major from global (L2-hot). No LDS staging, no K-loop barriers.
// Per chunk per wave: 7 b128 loads + 12 MFMA.
// ---------------------------------------------------------------------------
template<bool DUAL, bool RELU, bool DEG, bool STATS>
__global__ __launch_bounds__(256, 4) void gemm_mfma_k(
    const ushort* __restrict__ A1h, const ushort* __restrict__ W1f,
    const ushort* __restrict__ A2h, const ushort* __restrict__ W2f,
    const float* __restrict__ degf, const float* __restrict__ bias,
    float* __restrict__ C, float* __restrict__ stats, int N, int K)
{
    __shared__ float sstat[2][HDIM];
    const int tid  = threadIdx.x;
    const int wave = tid >> 6;      // 0..3 = column group (48 cols each)
    const int lane = tid & 63;
    const int row0 = blockIdx.x * 64;
    const int m16 = lane & 15;
    const int g4  = lane >> 4;

    if (STATS && tid < HDIM) { sstat[0][tid] = 0.f; sstat[1][tid] = 0.f; }

    int rowid[4];
    #pragma unroll
    for (int s = 0; s < 4; ++s) {
        int rr = row0 + s * 16 + m16; if (rr >= N) rr = N - 1;
        rowid[s] = rr;
    }

    floatx4 acc[4][3];
    #pragma unroll
    for (int s = 0; s < 4; ++s)
        #pragma unroll
        for (int ct = 0; ct < 3; ++ct) acc[s][ct] = (floatx4){0.f, 0.f, 0.f, 0.f};

    const int nkc = K >> 5;
    const int nphase = DUAL ? 2 : 1;
    for (int phase = 0; phase < nphase; ++phase) {
        const ushort* Ah = phase ? A2h : A1h;
        const ushort* Wf = phase ? W2f : W1f;
        for (int kc = 0; kc < nkc; ++kc) {
            const ushort* Wb = Wf + (size_t)kc * 6144 + (size_t)(wave * 3 * 64 + lane) * 8;
            half8 bh[3];
            #pragma unroll
            for (int ct = 0; ct < 3; ++ct)
                bh[ct] = *(const half8*)(Wb + ct * 512);
            // A fragments: chunk-planar -> one contiguous 1KB block per wave
            const ushort* Ap = Ah + (size_t)kc * N * 32 + g4 * 8;
            half8 ah[4];
            #pragma unroll
            for (int s = 0; s < 4; ++s)
                ah[s] = *(const half8*)(Ap + (size_t)rowid[s] * 32);
            #pragma unroll
            for (int ct = 0; ct < 3; ++ct)
                #pragma unroll
                for (int s = 0; s < 4; ++s)
                    acc[s][ct] = __builtin_amdgcn_mfma_f32_16x16x32_f16(ah[s], bh[ct], acc[s][ct], 0, 0, 0);
        }
    }

    if (STATS) __syncthreads();   // sstat zero-init visible

    // epilogue: C/D layout col=lane&15, row=(lane>>4)*4+reg  [m89]
    #pragma unroll
    for (int ct = 0; ct < 3; ++ct) {
        int col = wave * 48 + ct * 16 + m16;
        float bv = bias ? bias[col] : 0.f;
        float lsum = 0.f, lsq = 0.f;
        #pragma unroll
        for (int s = 0; s < 4; ++s) {
            #pragma unroll
            for (int reg = 0; reg < 4; ++reg) {
                int rr = row0 + s * 16 + g4 * 4 + reg;
                if (rr < N) {
                    float v = acc[s][ct][reg] + (DEG ? degf[rr] * bv : bv);
                    if (STATS) { lsum += v; lsq += v * v; }
                    if (RELU) v = fmaxf(v, 0.f);
                    C[(size_t)rr * HDIM + col] = v;
                }
            }
        }
        if (STATS) {
            lsum += __shfl_xor(lsum, 16); lsum += __shfl_xor(lsum, 32);
            lsq  += __shfl_xor(lsq, 16);  lsq  += __shfl_xor(lsq, 32);
            if (g4 == 0) {
                atomicAdd(&sstat[0][col], lsum);
                atomicAdd(&sstat[1][col], lsq);
            }
        }
    }
    if (STATS) {
        __syncthreads();
        if (tid < HDIM) {
            atomicAdd(&stats[tid], sstat[0][tid]);
            atomicAdd(&stats[HDIM + tid], sstat[1][tid]);
        }
    }
}

// ---------------------------------------------------------------------------
// CSR construction from edge_dst
// ---------------------------------------------------------------------------
__global__ __launch_bounds__(256) void hist_k(
    const int* __restrict__ dst, int* __restrict__ deg, int E)
{
    int e = blockIdx.x * 256 + threadIdx.x;
    if (e < E) atomicAdd(&deg[dst[e]], 1);
}

__global__ __launch_bounds__(256) void block_sum_k(
    const int* __restrict__ deg, int* __restrict__ bsum, int N)
{
    __shared__ int s[256];
    int t = threadIdx.x;
    int n = blockIdx.x * 256 + t;
    s[t] = (n < N) ? deg[n] : 0;
    __syncthreads();
    for (int off = 128; off > 0; off >>= 1) {
        if (t < off) s[t] += s[t + off];
        __syncthreads();
    }
    if (t == 0) bsum[blockIdx.x] = s[0];
}

__global__ __launch_bounds__(512) void scan_bsum_k(int* __restrict__ bsum, int nb)
{
    __shared__ int s[512];
    int t = threadIdx.x;
    int v = (t < nb) ? bsum[t] : 0;
    s[t] = v;
    __syncthreads();
    for (int off = 1; off < 512; off <<= 1) {
        int u = (t >= off) ? s[t - off] : 0;
        __syncthreads();
        s[t] += u;
        __syncthreads();
    }
    if (t < nb) bsum[t] = s[t] - v;   // exclusive
}

__global__ __launch_bounds__(256) void row_ptr_k(
    const int* __restrict__ deg, const int* __restrict__ bsum,
    int* __restrict__ row_ptr, int* __restrict__ cursor,
    float* __restrict__ degf, int N, int E)
{
    __shared__ int s[256];
    int t = threadIdx.x;
    int n = blockIdx.x * 256 + t;
    int v = (n < N) ? deg[n] : 0;
    s[t] = v;
    __syncthreads();
    for (int off = 1; off < 256; off <<= 1) {
        int u = (t >= off) ? s[t - off] : 0;
        __syncthreads();
        s[t] += u;
        __syncthreads();
    }
    int ex = s[t] - v + bsum[blockIdx.x];
    if (n < N) {
        row_ptr[n] = ex;
        cursor[n]  = ex;
        degf[n]    = (float)v;
    }
    if (blockIdx.x == 0 && t == 0) row_ptr[N] = E;
}

__global__ __launch_bounds__(256) void fill_k(
    const int* __restrict__ src, const int* __restrict__ dst,
    int* __restrict__ cursor, int* __restrict__ col, int E)
{
    int e = blockIdx.x * 256 + threadIdx.x;
    if (e < E) {
        int p = atomicAdd(&cursor[dst[e]], 1);
        col[p] = src[e];
    }
}

// ---------------------------------------------------------------------------
// gather on chunk-planar fp16: g[n] = sum_{j} x[col[j]]; fp32 acc, RTN out.
// One thread per (node, 8-channel octet).
// ---------------------------------------------------------------------------
__global__ __launch_bounds__(256) void gather_h_k(
    const ushort* __restrict__ xh, const int* __restrict__ row_ptr,
    const int* __restrict__ col, ushort* __restrict__ gh, int N, int K)
{
    int OC = K >> 3;
    int idx = blockIdx.x * 256 + threadIdx.x;
    if (idx >= N * OC) return;
    int n = idx / OC;
    int o = idx - n * OC;
    size_t plane = (size_t)(o >> 2) * N * 32 + (o & 3) * 8;   // chunk base + e0
    int j0 = row_ptr[n], j1 = row_ptr[n + 1];
    float acc[8] = {0.f,0.f,0.f,0.f,0.f,0.f,0.f,0.f};
    for (int j = j0; j < j1; ++j) {
        int s = col[j];
        uint4 hv = *(const uint4*)(xh + plane + (size_t)s * 32);
        uint hu[4] = {hv.x, hv.y, hv.z, hv.w};
        #pragma unroll
        for (int t = 0; t < 4; ++t) {
            acc[2*t]   += h2f((ushort)(hu[t] & 0xffffu));
            acc[2*t+1] += h2f((ushort)(hu[t] >> 16));
        }
    }
    ushort oh[8];
    #pragma unroll
    for (int t = 0; t < 8; ++t) oh[t] = f2h(acc[t]);
    *(uint4*)(gh + plane + (size_t)n * 32) = pack8(oh);
}

// ---------------------------------------------------------------------------
// batchnorm finalize + apply (chunk-planar fp16 out)
// ---------------------------------------------------------------------------
__global__ void bn_finalize_k(const float* __restrict__ sums,
                              const float* __restrict__ gamma,
                              const float* __restrict__ beta,
                              float* __restrict__ ss, float invN)
{
    int c = threadIdx.x;
    float mu  = sums[c] * invN;
    float var = sums[HDIM + c] * invN - mu * mu;
    float sc  = gamma[c] * rsqrtf(var + EPS);
    ss[c]        = sc;
    ss[HDIM + c] = beta[c] - mu * sc;
}

__global__ __launch_bounds__(256) void bn_apply_h_k(
    const float* __restrict__ h, const float* __restrict__ ss,
    ushort* __restrict__ xh, int N)
{
    int idx = blockIdx.x * 256 + threadIdx.x;   // over N*24 octets
    if (idx >= N * 24) return;
    int n = idx / 24;
    int o = idx - n * 24;
    int q = o * 8;
    float4 v0 = ((const float4*)h)[idx * 2];
    float4 v1 = ((const float4*)h)[idx * 2 + 1];
    float v[8] = {v0.x, v0.y, v0.z, v0.w, v1.x, v1.y, v1.z, v1.w};
    ushort oh[8];
    #pragma unroll
    for (int t = 0; t < 8; ++t) {
        float r = fmaxf(v[t] * ss[q + t] + ss[HDIM + q + t], 0.f);
        oh[t] = f2h(r);
    }
    *(uint4*)(xh + ((size_t)(o >> 2) * N + n) * 32 + (o & 3) * 8) = pack8(oh);
}

// ---------------------------------------------------------------------------
// pool over contiguous per-graph row ranges (batch sorted), planar input
// ---------------------------------------------------------------------------
__global__ __launch_bounds__(256) void init_start_k(int* __restrict__ start, int G, int N)
{
    int g = blockIdx.x * 256 + threadIdx.x;
    if (g <= G) start[g] = N;
}

__global__ __launch_bounds__(256) void bound_k(
    const int* __restrict__ batch, int* __restrict__ start, int N)
{
    int n = blockIdx.x * 256 + threadIdx.x;
    if (n >= N) return;
    int b  = batch[n];
    int bp = (n == 0) ? -1 : batch[n - 1];
    for (int g = bp + 1; g <= b; ++g) start[g] = n;
}

__global__ __launch_bounds__(192) void pool_k(
    const ushort* __restrict__ xh, const int* __restrict__ start,
    float* __restrict__ gout, int G, int N)
{
    int g = blockIdx.x;
    int c = threadIdx.x;
    const ushort* base = xh + (size_t)(c >> 5) * N * 32 + (c & 31);
    int r0 = start[g], r1 = start[g + 1];
    float s = 0.f;
    for (int r = r0; r < r1; ++r) s += h2f(base[(size_t)r * 32]);
    float cnt = (float)(r1 - r0);
    gout[(size_t)g * HDIM + c] = s / fmaxf(cnt, 1.f);
}

// ---------------------------------------------------------------------------
__global__ __launch_bounds__(64) void out_dot_k(
    const float* __restrict__ g2, const float* __restrict__ Wout,
    const float* __restrict__ bout, float* __restrict__ out, int G)
{
    int gi = blockIdx.x;
    int t = threadIdx.x;
    const float* r = g2 + (size_t)gi * HDIM;
    float s = r[t] * Wout[t] + r[t + 64] * Wout[t + 64] + r[t + 128] * Wout[t + 128];
    #pragma unroll
    for (int off = 32; off > 0; off >>= 1) s += __shfl_down(s, off, 64);
    if (t == 0) out[gi] = s + bout[0];
}

// ---------------------------------------------------------------------------
extern "C" void kernel_launch(void* const* d_in, const int* in_sizes, int n_in,
                              void* d_out, int out_size, void* d_ws, size_t ws_size,
                              hipStream_t stream)
{
    const float* x      = (const float*)d_in[0];
    const int*   esrc   = (const int*)d_in[1];
    const int*   edst   = (const int*)d_in[2];
    const int*   batch  = (const int*)d_in[3];
    const float* Wrel0  = (const float*)d_in[4];
    const float* brel0  = (const float*)d_in[5];
    const float* Wroot0 = (const float*)d_in[6];
    const float* Wrel   = (const float*)d_in[7];
    const float* brel   = (const float*)d_in[8];
    const float* Wroot  = (const float*)d_in[9];
    const float* gamma  = (const float*)d_in[10];
    const float* beta   = (const float*)d_in[11];
    const float* Wh1    = (const float*)d_in[12];
    const float* bh1    = (const float*)d_in[13];
    const float* Wh2    = (const float*)d_in[14];
    const float* bh2    = (const float*)d_in[15];
    const float* Wout   = (const float*)d_in[16];
    const float* bout   = (const float*)d_in[17];
    float* out = (float*)d_out;

    const int N  = in_sizes[3];           // 100000
    const int E  = in_sizes[1];           // 400000
    const int K0 = in_sizes[0] / N;       // 32
    const int G  = out_size;              // 2000
    const int nBlocks = (N + 255) / 256;

    char* p = (char*)d_ws;
    auto carve = [&](size_t bytes) -> void* {
        void* r = (void*)p; p += (bytes + 255) & ~(size_t)255; return r;
    };
    float*  bufa  = (float*) carve((size_t)N * HDIM * 4);
    ushort* xh    = (ushort*)carve((size_t)N * HDIM * 2);
    ushort* gh    = (ushort*)carve((size_t)N * HDIM * 2);
    float*  gsum  = (float*) carve((size_t)G * HDIM * 4);
    float*  g1    = (float*) carve((size_t)G * HDIM * 4);
    float*  g2    = (float*) carve((size_t)G * HDIM * 4);
    ushort* gsh   = (ushort*)carve((size_t)G * HDIM * 2);
    ushort* g1h   = (ushort*)carve((size_t)G * HDIM * 2);
    float*  bnsums= (float*) carve(4 * 2 * HDIM * 4);   // per-layer slices
    float*  bnss  = (float*) carve(2 * HDIM * 4);
    float*  degf  = (float*) carve((size_t)N * 4);
    int*    deg   = (int*)   carve((size_t)N * 4);
    int*    row_ptr=(int*)   carve((size_t)(N + 1) * 4);
    int*    cursor= (int*)   carve((size_t)N * 4);
    int*    col   = (int*)   carve((size_t)E * 4);
    int*    bsum  = (int*)   carve((size_t)nBlocks * 4);
    int*    start = (int*)   carve((size_t)(G + 1) * 4);
    ushort* Wrel0f= (ushort*)carve((size_t)K0 * HDIM * 2);
    ushort* Wroot0f=(ushort*)carve((size_t)K0 * HDIM * 2);
    ushort* Wrelf = (ushort*)carve((size_t)3 * HDIM * HDIM * 2);
    ushort* Wrootf= (ushort*)carve((size_t)3 * HDIM * HDIM * 2);
    ushort* Wh1f  = (ushort*)carve((size_t)HDIM * HDIM * 2);
    ushort* Wh2f  = (ushort*)carve((size_t)HDIM * HDIM * 2);

    dim3 b256(256);
    const int eBlocks = (E + 255) / 256;
    const int gemmN = (N + 63) / 64;
    const int gemmG = (G + 63) / 64;

    // ---- weight prep (frag-ordered single fp16 plane)
    {
        int t0 = (K0 >> 5) * 12 * 64;
        int t1 = (HDIM >> 5) * 12 * 64;
        prep_w_k<<<(t0 + 255) / 256, b256, 0, stream>>>(Wrel0,  Wrel0f,  K0, 1);
        prep_w_k<<<(t0 + 255) / 256, b256, 0, stream>>>(Wroot0, Wroot0f, K0, 1);
        prep_w_k<<<(3 * t1 + 255) / 256, b256, 0, stream>>>(Wrel,  Wrelf,  HDIM, 3);
        prep_w_k<<<(3 * t1 + 255) / 256, b256, 0, stream>>>(Wroot, Wrootf, HDIM, 3);
        prep_w_k<<<(t1 + 255) / 256, b256, 0, stream>>>(Wh1, Wh1f, HDIM, 1);
        prep_w_k<<<(t1 + 255) / 256, b256, 0, stream>>>(Wh2, Wh2f, HDIM, 1);
    }
    // x -> planar fp16 (K0=32: planar == row-major)
    conv_planar_k<<<((N * (K0 >> 3)) + 255) / 256, b256, 0, stream>>>(x, xh, N, K0);

    // ---- CSR build
    hipMemsetAsync(deg, 0, N * sizeof(int), stream);
    hipMemsetAsync(bnsums, 0, 4 * 2 * HDIM * sizeof(float), stream);
    hist_k<<<eBlocks, b256, 0, stream>>>(edst, deg, E);
    block_sum_k<<<nBlocks, b256, 0, stream>>>(deg, bsum, N);
    scan_bsum_k<<<1, dim3(512), 0, stream>>>(bsum, nBlocks);
    row_ptr_k<<<nBlocks, b256, 0, stream>>>(deg, bsum, row_ptr, cursor, degf, N, E);
    fill_k<<<eBlocks, b256, 0, stream>>>(esrc, edst, cursor, col, E);

    // ---- graph boundaries for pooling
    init_start_k<<<(G + 256) / 256, b256, 0, stream>>>(start, G, N);
    bound_k<<<nBlocks, b256, 0, stream>>>(batch, start, N);

    // ---- layers
    for (int l = 0; l < 4; ++l) {
        const int K = (l == 0) ? K0 : HDIM;
        const ushort* Wrf = (l == 0) ? Wrel0f  : Wrelf  + (size_t)(l - 1) * HDIM * HDIM;
        const ushort* Wtf = (l == 0) ? Wroot0f : Wrootf + (size_t)(l - 1) * HDIM * HDIM;
        const float*  br  = (l == 0) ? brel0   : brel   + (size_t)(l - 1) * HDIM;
        float* stats = bnsums + l * 2 * HDIM;

        int gthreads = N * (K >> 3);
        gather_h_k<<<(gthreads + 255) / 256, b256, 0, stream>>>(
            xh, row_ptr, col, gh, N, K);
        gemm_mfma_k<true, false, true, true><<<gemmN, b256, 0, stream>>>(
            gh, Wrf, xh, Wtf, degf, br, bufa, stats, N, K);
        bn_finalize_k<<<1, dim3(192), 0, stream>>>(stats, gamma + l * HDIM,
                                                   beta + l * HDIM, bnss, 1.0f / N);
        bn_apply_h_k<<<(N * 24 + 255) / 256, b256, 0, stream>>>(bufa, bnss, xh, N);
    }

    // ---- pool
    pool_k<<<G, dim3(192), 0, stream>>>(xh, start, gsum, G, N);

    // ---- head MLP (MFMA path, planar activations with Nrow=G)
    conv_planar_k<<<((G * 24) + 255) / 256, b256, 0, stream>>>(gsum, gsh, G, HDIM);
    gemm_mfma_k<false, true, false, false><<<gemmG, b256, 0, stream>>>(
        gsh, Wh1f, nullptr, nullptr, nullptr, bh1, g1, nullptr, G, HDIM);
    conv_planar_k<<<((G * 24) + 255) / 256, b256, 0, stream>>>(g1, g1h, G, HDIM);
    gemm_mfma_k<false, false, false, false><<<gemmG, b256, 0, stream>>>(
        g1h, Wh2f, nullptr, nullptr, nullptr, bh2, g2, nullptr, G, HDIM);
    out_dot_k<<<G, dim3(64), 0, stream>>>(g2, Wout, bout, out, G);
}

// Round 11
// 671.596 us; speedup vs baseline: 1.1664x; 1.1037x over previous
//
#include <hip/hip_runtime.h>

#define HDIM 192
#define EPS 1e-5f

typedef __attribute__((ext_vector_type(8))) _Float16 half8;
typedef __attribute__((ext_vector_type(4))) float floatx4;

__device__ __forceinline__ float h2f(ushort u) {
    union { ushort u; _Float16 h; } c; c.u = u; return (float)c.h;
}
__device__ __forceinline__ ushort f2h(float x) {
    _Float16 h = (_Float16)x;           // RTN
    union { _Float16 h; ushort u; } c; c.h = h; return c.u;
}
__device__ __forceinline__ uint4 pack8(const ushort* h) {
    uint4 p;
    p.x = h[0] | ((uint)h[1] << 16); p.y = h[2] | ((uint)h[3] << 16);
    p.z = h[4] | ((uint)h[5] << 16); p.w = h[6] | ((uint)h[7] << 16);
    return p;
}

// Activation planes are CHUNK-PLANAR: element (row, c) lives at
// ((c/32)*Nrow + row)*32 + c%32.  GEMM A-frag loads read a contiguous 1KB
// block per wave; GEMM C-writes, bn_apply, gather all use the same layout.

// ---------------------------------------------------------------------------
// Weight prep: W[K,192] fp32 (nmat stacked) -> frag-ordered SINGLE fp16 plane.
// Per k-chunk (32 k): [ct(12)][lane(64)][j(8)] = 6144 ushorts.
// B-frag layout of mfma_f32_16x16x32_f16: n=lane&15, k=(lane>>4)*8+j.
// ---------------------------------------------------------------------------
__global__ __launch_bounds__(256) void prep_w_k(
    const float* __restrict__ W, ushort* __restrict__ Wf, int K, int nmat)
{
    int perMat = (K >> 5) * 12 * 64;
    int idx = blockIdx.x * 256 + threadIdx.x;
    if (idx >= perMat * nmat) return;
    int mat = idx / perMat;
    int r = idx - mat * perMat;
    int lane = r & 63;
    int ct = (r >> 6) % 12;
    int kc = r / (12 * 64);
    int col = ct * 16 + (lane & 15);
    int kb  = kc * 32 + (lane >> 4) * 8;
    const float* Wm = W + (size_t)mat * K * HDIM;
    ushort* base = Wf + (size_t)mat * K * HDIM;
    size_t o = (size_t)kc * 6144 + (size_t)(ct * 64 + lane) * 8;
    #pragma unroll
    for (int j = 0; j < 8; ++j)
        base[o + j] = f2h(Wm[(size_t)(kb + j) * HDIM + col]);
}

// ---------------------------------------------------------------------------
// fp32 row-major [R, C] -> fp16 chunk-planar. One thread per 8 channels.
// ---------------------------------------------------------------------------
__global__ __launch_bounds__(256) void conv_planar_k(
    const float* __restrict__ src, ushort* __restrict__ dst, int R, int C)
{
    int OC = C >> 3;
    int idx = blockIdx.x * 256 + threadIdx.x;
    if (idx >= R * OC) return;
    int r = idx / OC;
    int o = idx - r * OC;
    float4 v0 = ((const float4*)(src + (size_t)r * C + o * 8))[0];
    float4 v1 = ((const float4*)(src + (size_t)r * C + o * 8))[1];
    float v[8] = {v0.x, v0.y, v0.z, v0.w, v1.x, v1.y, v1.z, v1.w};
    ushort h[8];
    #pragma unroll
    for (int t = 0; t < 8; ++t) h[t] = f2h(v[t]);
    *(uint4*)(dst + ((size_t)(o >> 2) * R + r) * 32 + (o & 3) * 8) = pack8(h);
}

// ---------------------------------------------------------------------------
// MFMA GEMM: C[N,192] = A1@W1 (+ A2@W2) + bias-term, optional fused BN stats.
// Block: 256 thr / 4 waves, tile 64 rows x 192 cols; wave tile 64x48.
// A chunk-planar fp16; W single fp16 plane frag-major (L2-hot); both loaded
// straight from global, no LDS, no K-loop barriers.  Register double-buffer:
// chunk c+1's 7 b128 loads issue during chunk c's MFMAs (2x outstanding).
// C output written as fp16 CHUNK-PLANAR (BN stats taken from fp32 accs).
// ---------------------------------------------------------------------------
template<bool DUAL, bool RELU, bool DEG, bool STATS>
__global__ __launch_bounds__(256, 3) void gemm_mfma_k(
    const ushort* __restrict__ A1h, const ushort* __restrict__ W1f,
    const ushort* __restrict__ A2h, const ushort* __restrict__ W2f,
    const float* __restrict__ degf, const float* __restrict__ bias,
    ushort* __restrict__ C, float* __restrict__ stats, int N, int K)
{
    __shared__ float sstat[2][HDIM];
    const int tid  = threadIdx.x;
    const int wave = tid >> 6;      // 0..3 = column group (48 cols each)
    const int lane = tid & 63;
    const int row0 = blockIdx.x * 64;
    const int m16 = lane & 15;
    const int g4  = lane >> 4;

    if (STATS && tid < HDIM) { sstat[0][tid] = 0.f; sstat[1][tid] = 0.f; }

    int rowid[4];
    #pragma unroll
    for (int s = 0; s < 4; ++s) {
        int rr = row0 + s * 16 + m16; if (rr >= N) rr = N - 1;
        rowid[s] = rr;
    }

    floatx4 acc[4][3];
    #pragma unroll
    for (int s = 0; s < 4; ++s)
        #pragma unroll
        for (int ct = 0; ct < 3; ++ct) acc[s][ct] = (floatx4){0.f, 0.f, 0.f, 0.f};

    const int nkc = K >> 5;
    const int nch = DUAL ? 2 * nkc : nkc;   // always even here

    auto loadc = [&](int c, half8* a, half8* b) {
        bool ph = DUAL && (c >= nkc);
        int kc = ph ? c - nkc : c;
        const ushort* Ap = (ph ? A2h : A1h) + (size_t)kc * N * 32 + g4 * 8;
        #pragma unroll
        for (int s = 0; s < 4; ++s)
            a[s] = *(const half8*)(Ap + (size_t)rowid[s] * 32);
        const ushort* Bp = (ph ? W2f : W1f) + (size_t)kc * 6144
                         + (size_t)(wave * 192 + lane) * 8;
        #pragma unroll
        for (int ct = 0; ct < 3; ++ct)
            b[ct] = *(const half8*)(Bp + ct * 512);
    };
    auto domfma = [&](half8* a, half8* b) {
        #pragma unroll
        for (int ct = 0; ct < 3; ++ct)
            #pragma unroll
            for (int s = 0; s < 4; ++s)
                acc[s][ct] = __builtin_amdgcn_mfma_f32_16x16x32_f16(a[s], b[ct], acc[s][ct], 0, 0, 0);
    };

    half8 a0[4], b0[3], a1[4], b1[3];
    loadc(0, a0, b0);
    for (int cc = 0; cc < nch; cc += 2) {
        if (cc + 1 < nch) loadc(cc + 1, a1, b1);
        domfma(a0, b0);
        if (cc + 2 < nch) loadc(cc + 2, a0, b0);
        if (cc + 1 < nch) domfma(a1, b1);
    }

    if (STATS) __syncthreads();   // sstat zero-init visible

    // epilogue: C/D layout col=lane&15, row=(lane>>4)*4+reg  [m89]
    // C written fp16 chunk-planar: ((col/32)*N + rr)*32 + col%32
    #pragma unroll
    for (int ct = 0; ct < 3; ++ct) {
        int col = wave * 48 + ct * 16 + m16;
        float bv = bias ? bias[col] : 0.f;
        ushort* Cc = C + (size_t)(col >> 5) * N * 32 + (col & 31);
        float lsum = 0.f, lsq = 0.f;
        #pragma unroll
        for (int s = 0; s < 4; ++s) {
            #pragma unroll
            for (int reg = 0; reg < 4; ++reg) {
                int rr = row0 + s * 16 + g4 * 4 + reg;
                if (rr < N) {
                    float v = acc[s][ct][reg] + (DEG ? degf[rr] * bv : bv);
                    if (STATS) { lsum += v; lsq += v * v; }
                    if (RELU) v = fmaxf(v, 0.f);
                    Cc[(size_t)rr * 32] = f2h(v);
                }
            }
        }
        if (STATS) {
            lsum += __shfl_xor(lsum, 16); lsum += __shfl_xor(lsum, 32);
            lsq  += __shfl_xor(lsq, 16);  lsq  += __shfl_xor(lsq, 32);
            if (g4 == 0) {
                atomicAdd(&sstat[0][col], lsum);
                atomicAdd(&sstat[1][col], lsq);
            }
        }
    }
    if (STATS) {
        __syncthreads();
        if (tid < HDIM) {
            atomicAdd(&stats[tid], sstat[0][tid]);
            atomicAdd(&stats[HDIM + tid], sstat[1][tid]);
        }
    }
}

// ---------------------------------------------------------------------------
// CSR construction from edge_dst
// ---------------------------------------------------------------------------
__global__ __launch_bounds__(256) void hist_k(
    const int* __restrict__ dst, int* __restrict__ deg, int E)
{
    int e = blockIdx.x * 256 + threadIdx.x;
    if (e < E) atomicAdd(&deg[dst[e]], 1);
}

__global__ __launch_bounds__(256) void block_sum_k(
    const int* __restrict__ deg, int* __restrict__ bsum, int N)
{
    __shared__ int s[256];
    int t = threadIdx.x;
    int n = blockIdx.x * 256 + t;
    s[t] = (n < N) ? deg[n] : 0;
    __syncthreads();
    for (int off = 128; off > 0; off >>= 1) {
        if (t < off) s[t] += s[t + off];
        __syncthreads();
    }
    if (t == 0) bsum[blockIdx.x] = s[0];
}

__global__ __launch_bounds__(512) void scan_bsum_k(int* __restrict__ bsum, int nb)
{
    __shared__ int s[512];
    int t = threadIdx.x;
    int v = (t < nb) ? bsum[t] : 0;
    s[t] = v;
    __syncthreads();
    for (int off = 1; off < 512; off <<= 1) {
        int u = (t >= off) ? s[t - off] : 0;
        __syncthreads();
        s[t] += u;
        __syncthreads();
    }
    if (t < nb) bsum[t] = s[t] - v;   // exclusive
}

__global__ __launch_bounds__(256) void row_ptr_k(
    const int* __restrict__ deg, const int* __restrict__ bsum,
    int* __restrict__ row_ptr, int* __restrict__ cursor,
    float* __restrict__ degf, int N, int E)
{
    __shared__ int s[256];
    int t = threadIdx.x;
    int n = blockIdx.x * 256 + t;
    int v = (n < N) ? deg[n] : 0;
    s[t] = v;
    __syncthreads();
    for (int off = 1; off < 256; off <<= 1) {
        int u = (t >= off) ? s[t - off] : 0;
        __syncthreads();
        s[t] += u;
        __syncthreads();
    }
    int ex = s[t] - v + bsum[blockIdx.x];
    if (n < N) {
        row_ptr[n] = ex;
        cursor[n]  = ex;
        degf[n]    = (float)v;
    }
    if (blockIdx.x == 0 && t == 0) row_ptr[N] = E;
}

__global__ __launch_bounds__(256) void fill_k(
    const int* __restrict__ src, const int* __restrict__ dst,
    int* __restrict__ cursor, int* __restrict__ col, int E)
{
    int e = blockIdx.x * 256 + threadIdx.x;
    if (e < E) {
        int p = atomicAdd(&cursor[dst[e]], 1);
        col[p] = src[e];
    }
}

// ---------------------------------------------------------------------------
// gather on chunk-planar fp16: g[n] = sum_{j} x[col[j]]; fp32 acc, RTN out.
// One thread per (node, 8-channel octet).
// ---------------------------------------------------------------------------
__global__ __launch_bounds__(256) void gather_h_k(
    const ushort* __restrict__ xh, const int* __restrict__ row_ptr,
    const int* __restrict__ col, ushort* __restrict__ gh, int N, int K)
{
    int OC = K >> 3;
    int idx = blockIdx.x * 256 + threadIdx.x;
    if (idx >= N * OC) return;
    int n = idx / OC;
    int o = idx - n * OC;
    size_t plane = (size_t)(o >> 2) * N * 32 + (o & 3) * 8;   // chunk base + e0
    int j0 = row_ptr[n], j1 = row_ptr[n + 1];
    float acc[8] = {0.f,0.f,0.f,0.f,0.f,0.f,0.f,0.f};
    for (int j = j0; j < j1; ++j) {
        int s = col[j];
        uint4 hv = *(const uint4*)(xh + plane + (size_t)s * 32);
        uint hu[4] = {hv.x, hv.y, hv.z, hv.w};
        #pragma unroll
        for (int t = 0; t < 4; ++t) {
            acc[2*t]   += h2f((ushort)(hu[t] & 0xffffu));
            acc[2*t+1] += h2f((ushort)(hu[t] >> 16));
        }
    }
    ushort oh[8];
    #pragma unroll
    for (int t = 0; t < 8; ++t) oh[t] = f2h(acc[t]);
    *(uint4*)(gh + plane + (size_t)n * 32) = pack8(oh);
}

// ---------------------------------------------------------------------------
// batchnorm finalize + apply (fp16 planar in, fp16 planar out)
// ---------------------------------------------------------------------------
__global__ void bn_finalize_k(const float* __restrict__ sums,
                              const float* __restrict__ gamma,
                              const float* __restrict__ beta,
                              float* __restrict__ ss, float invN)
{
    int c = threadIdx.x;
    float mu  = sums[c] * invN;
    float var = sums[HDIM + c] * invN - mu * mu;
    float sc  = gamma[c] * rsqrtf(var + EPS);
    ss[c]        = sc;
    ss[HDIM + c] = beta[c] - mu * sc;
}

__global__ __launch_bounds__(256) void bn_apply_h_k(
    const ushort* __restrict__ h, const float* __restrict__ ss,
    ushort* __restrict__ xh, int N)
{
    int idx = blockIdx.x * 256 + threadIdx.x;   // over N*24 octets
    if (idx >= N * 24) return;
    int n = idx / 24;
    int o = idx - n * 24;
    int q = o * 8;
    size_t off = ((size_t)(o >> 2) * N + n) * 32 + (o & 3) * 8;
    uint4 hv = *(const uint4*)(h + off);
    uint hu[4] = {hv.x, hv.y, hv.z, hv.w};
    ushort oh[8];
    #pragma unroll
    for (int t = 0; t < 4; ++t) {
        float v0 = h2f((ushort)(hu[t] & 0xffffu));
        float v1 = h2f((ushort)(hu[t] >> 16));
        oh[2*t]   = f2h(fmaxf(v0 * ss[q + 2*t]     + ss[HDIM + q + 2*t],     0.f));
        oh[2*t+1] = f2h(fmaxf(v1 * ss[q + 2*t + 1] + ss[HDIM + q + 2*t + 1], 0.f));
    }
    *(uint4*)(xh + off) = pack8(oh);
}

// ---------------------------------------------------------------------------
// pool over contiguous per-graph row ranges (batch sorted), planar input
// ---------------------------------------------------------------------------
__global__ __launch_bounds__(256) void init_start_k(int* __restrict__ start, int G, int N)
{
    int g = blockIdx.x * 256 + threadIdx.x;
    if (g <= G) start[g] = N;
}

__global__ __launch_bounds__(256) void bound_k(
    const int* __restrict__ batch, int* __restrict__ start, int N)
{
    int n = blockIdx.x * 256 + threadIdx.x;
    if (n >= N) return;
    int b  = batch[n];
    int bp = (n == 0) ? -1 : batch[n - 1];
    for (int g = bp + 1; g <= b; ++g) start[g] = n;
}

__global__ __launch_bounds__(192) void pool_k(
    const ushort* __restrict__ xh, const int* __restrict__ start,
    float* __restrict__ gout, int G, int N)
{
    int g = blockIdx.x;
    int c = threadIdx.x;
    const ushort* base = xh + (size_t)(c >> 5) * N * 32 + (c & 31);
    int r0 = start[g], r1 = start[g + 1];
    float s = 0.f;
    for (int r = r0; r < r1; ++r) s += h2f(base[(size_t)r * 32]);
    float cnt = (float)(r1 - r0);
    gout[(size_t)g * HDIM + c] = s / fmaxf(cnt, 1.f);
}

// ---------------------------------------------------------------------------
// out[g] = dot(g2[g,:], Wout) + bout ; g2 is fp16 chunk-planar
// ---------------------------------------------------------------------------
__global__ __launch_bounds__(64) void out_dot_k(
    const ushort* __restrict__ g2h, const float* __restrict__ Wout,
    const float* __restrict__ bout, float* __restrict__ out, int G)
{
    int gi = blockIdx.x;
    int t = threadIdx.x;
    float s = 0.f;
    #pragma unroll
    for (int j = 0; j < 3; ++j) {
        int c = t + j * 64;
        s += h2f(g2h[((size_t)(c >> 5) * G + gi) * 32 + (c & 31)]) * Wout[c];
    }
    #pragma unroll
    for (int off = 32; off > 0; off >>= 1) s += __shfl_down(s, off, 64);
    if (t == 0) out[gi] = s + bout[0];
}

// ---------------------------------------------------------------------------
extern "C" void kernel_launch(void* const* d_in, const int* in_sizes, int n_in,
                              void* d_out, int out_size, void* d_ws, size_t ws_size,
                              hipStream_t stream)
{
    const float* x      = (const float*)d_in[0];
    const int*   esrc   = (const int*)d_in[1];
    const int*   edst   = (const int*)d_in[2];
    const int*   batch  = (const int*)d_in[3];
    const float* Wrel0  = (const float*)d_in[4];
    const float* brel0  = (const float*)d_in[5];
    const float* Wroot0 = (const float*)d_in[6];
    const float* Wrel   = (const float*)d_in[7];
    const float* brel   = (const float*)d_in[8];
    const float* Wroot  = (const float*)d_in[9];
    const float* gamma  = (const float*)d_in[10];
    const float* beta   = (const float*)d_in[11];
    const float* Wh1    = (const float*)d_in[12];
    const float* bh1    = (const float*)d_in[13];
    const float* Wh2    = (const float*)d_in[14];
    const float* bh2    = (const float*)d_in[15];
    const float* Wout   = (const float*)d_in[16];
    const float* bout   = (const float*)d_in[17];
    float* out = (float*)d_out;

    const int N  = in_sizes[3];           // 100000
    const int E  = in_sizes[1];           // 400000
    const int K0 = in_sizes[0] / N;       // 32
    const int G  = out_size;              // 2000
    const int nBlocks = (N + 255) / 256;

    char* p = (char*)d_ws;
    auto carve = [&](size_t bytes) -> void* {
        void* r = (void*)p; p += (bytes + 255) & ~(size_t)255; return r;
    };
    ushort* bufa_h= (ushort*)carve((size_t)N * HDIM * 2);   // raw conv, planar fp16
    ushort* xh    = (ushort*)carve((size_t)N * HDIM * 2);
    ushort* gh    = (ushort*)carve((size_t)N * HDIM * 2);
    float*  gsum  = (float*) carve((size_t)G * HDIM * 4);
    ushort* gsh   = (ushort*)carve((size_t)G * HDIM * 2);
    ushort* g1h   = (ushort*)carve((size_t)G * HDIM * 2);
    ushort* g2h   = (ushort*)carve((size_t)G * HDIM * 2);
    float*  bnsums= (float*) carve(4 * 2 * HDIM * 4);       // per-layer slices
    float*  bnss  = (float*) carve(2 * HDIM * 4);
    float*  degf  = (float*) carve((size_t)N * 4);
    int*    deg   = (int*)   carve((size_t)N * 4);
    int*    row_ptr=(int*)   carve((size_t)(N + 1) * 4);
    int*    cursor= (int*)   carve((size_t)N * 4);
    int*    col   = (int*)   carve((size_t)E * 4);
    int*    bsum  = (int*)   carve((size_t)nBlocks * 4);
    int*    start = (int*)   carve((size_t)(G + 1) * 4);
    ushort* Wrel0f= (ushort*)carve((size_t)K0 * HDIM * 2);
    ushort* Wroot0f=(ushort*)carve((size_t)K0 * HDIM * 2);
    ushort* Wrelf = (ushort*)carve((size_t)3 * HDIM * HDIM * 2);
    ushort* Wrootf= (ushort*)carve((size_t)3 * HDIM * HDIM * 2);
    ushort* Wh1f  = (ushort*)carve((size_t)HDIM * HDIM * 2);
    ushort* Wh2f  = (ushort*)carve((size_t)HDIM * HDIM * 2);

    dim3 b256(256);
    const int eBlocks = (E + 255) / 256;
    const int gemmN = (N + 63) / 64;
    const int gemmG = (G + 63) / 64;

    // ---- weight prep (frag-ordered single fp16 plane)
    {
        int t0 = (K0 >> 5) * 12 * 64;
        int t1 = (HDIM >> 5) * 12 * 64;
        prep_w_k<<<(t0 + 255) / 256, b256, 0, stream>>>(Wrel0,  Wrel0f,  K0, 1);
        prep_w_k<<<(t0 + 255) / 256, b256, 0, stream>>>(Wroot0, Wroot0f, K0, 1);
        prep_w_k<<<(3 * t1 + 255) / 256, b256, 0, stream>>>(Wrel,  Wrelf,  HDIM, 3);
        prep_w_k<<<(3 * t1 + 255) / 256, b256, 0, stream>>>(Wroot, Wrootf, HDIM, 3);
        prep_w_k<<<(t1 + 255) / 256, b256, 0, stream>>>(Wh1, Wh1f, HDIM, 1);
        prep_w_k<<<(t1 + 255) / 256, b256, 0, stream>>>(Wh2, Wh2f, HDIM, 1);
    }
    // x -> planar fp16 (K0=32: planar == row-major)
    conv_planar_k<<<((N * (K0 >> 3)) + 255) / 256, b256, 0, stream>>>(x, xh, N, K0);

    // ---- CSR build
    hipMemsetAsync(deg, 0, N * sizeof(int), stream);
    hipMemsetAsync(bnsums, 0, 4 * 2 * HDIM * sizeof(float), stream);
    hist_k<<<eBlocks, b256, 0, stream>>>(edst, deg, E);
    block_sum_k<<<nBlocks, b256, 0, stream>>>(deg, bsum, N);
    scan_bsum_k<<<1, dim3(512), 0, stream>>>(bsum, nBlocks);
    row_ptr_k<<<nBlocks, b256, 0, stream>>>(deg, bsum, row_ptr, cursor, degf, N, E);
    fill_k<<<eBlocks, b256, 0, stream>>>(esrc, edst, cursor, col, E);

    // ---- graph boundaries for pooling
    init_start_k<<<(G + 256) / 256, b256, 0, stream>>>(start, G, N);
    bound_k<<<nBlocks, b256, 0, stream>>>(batch, start, N);

    // ---- layers
    for (int l = 0; l < 4; ++l) {
        const int K = (l == 0) ? K0 : HDIM;
        const ushort* Wrf = (l == 0) ? Wrel0f  : Wrelf  + (size_t)(l - 1) * HDIM * HDIM;
        const ushort* Wtf = (l == 0) ? Wroot0f : Wrootf + (size_t)(l - 1) * HDIM * HDIM;
        const float*  br  = (l == 0) ? brel0   : brel   + (size_t)(l - 1) * HDIM;
        float* stats = bnsums + l * 2 * HDIM;

        int gthreads = N * (K >> 3);
        gather_h_k<<<(gthreads + 255) / 256, b256, 0, stream>>>(
            xh, row_ptr, col, gh, N, K);
        gemm_mfma_k<true, false, true, true><<<gemmN, b256, 0, stream>>>(
            gh, Wrf, xh, Wtf, degf, br, bufa_h, stats, N, K);
        bn_finalize_k<<<1, dim3(192), 0, stream>>>(stats, gamma + l * HDIM,
                                                   beta + l * HDIM, bnss, 1.0f / N);
        bn_apply_h_k<<<(N * 24 + 255) / 256, b256, 0, stream>>>(bufa_h, bnss, xh, N);
    }

    // ---- pool
    pool_k<<<G, dim3(192), 0, stream>>>(xh, start, gsum, G, N);

    // ---- head MLP (MFMA path, planar fp16 end-to-end)
    conv_planar_k<<<((G * 24) + 255) / 256, b256, 0, stream>>>(gsum, gsh, G, HDIM);
    gemm_mfma_k<false, true, false, false><<<gemmG, b256, 0, stream>>>(
        gsh, Wh1f, nullptr, nullptr, nullptr, bh1, g1h, nullptr, G, HDIM);
    gemm_mfma_k<false, false, false, false><<<gemmG, b256, 0, stream>>>(
        g1h, Wh2f, nullptr, nullptr, nullptr, bh2, g2h, nullptr, G, HDIM);
    out_dot_k<<<G, dim3(64), 0, stream>>>(g2h, Wout, bout, out, G);
}